// Round 8
// baseline (395.148 us; speedup 1.0000x reference)
//
#include <hip/hip_runtime.h>

#define N_NODES 50000
#define N_EDGES 800000
#define N_GRAPHS 128
#define IN_CH 31
#define HID 64

// ---------------- CSR build ----------------
// 1 edge/thread: atomic-latency bound -> maximize TLP (round 7: int4/thread
// shrank grid to 38% of wave slots, occupancy 27%, scatter 48 us).

__global__ void hist_kernel(const int* __restrict__ dst, int* __restrict__ counts, int e) {
    int i = blockIdx.x * 256 + threadIdx.x;
    if (i < e) atomicAdd(&counts[dst[i]], 1);
}

__global__ void scan_blocks_kernel(const int* __restrict__ counts, int* __restrict__ row_ptr,
                                   int* __restrict__ blk, int n) {
    __shared__ int tmp[256];
    int tid = threadIdx.x;
    int i = blockIdx.x * 256 + tid;
    int v = (i < n) ? counts[i] : 0;
    tmp[tid] = v;
    __syncthreads();
    for (int off = 1; off < 256; off <<= 1) {
        int u = (tid >= off) ? tmp[tid - off] : 0;
        __syncthreads();
        tmp[tid] += u;
        __syncthreads();
    }
    if (i < n) row_ptr[i + 1] = tmp[tid];
    if (tid == 255) blk[blockIdx.x] = tmp[255];
}

__global__ void scan_partials_kernel(int* __restrict__ blk, int nb) {
    __shared__ int tmp[256];
    int tid = threadIdx.x;
    int v = (tid < nb) ? blk[tid] : 0;
    tmp[tid] = v;
    __syncthreads();
    for (int off = 1; off < 256; off <<= 1) {
        int u = (tid >= off) ? tmp[tid - off] : 0;
        __syncthreads();
        tmp[tid] += u;
        __syncthreads();
    }
    if (tid < nb) blk[tid] = tmp[tid] - v;  // exclusive prefix
}

// also fills cursor[] = start offsets so scatter needs no second memset
__global__ void scan_add_kernel(int* __restrict__ row_ptr, const int* __restrict__ blk,
                                int* __restrict__ cursor, int n) {
    int i = blockIdx.x * 256 + threadIdx.x;
    if (i < n) {
        int v = row_ptr[i + 1] + blk[blockIdx.x];
        row_ptr[i + 1] = v;
        cursor[i + 1] = v;
    }
    if (i == 0) { row_ptr[0] = 0; cursor[0] = 0; }
}

__global__ void scatter_kernel(const int* __restrict__ src, const int* __restrict__ dst,
                               int* __restrict__ cursor, int* __restrict__ csr_src, int e) {
    int i = blockIdx.x * 256 + threadIdx.x;
    if (i < e) {
        int pos = atomicAdd(&cursor[dst[i]], 1);
        csr_src[pos] = src[i];
    }
}

// ---------------- aggregation kernel (no LDS, no barriers) ----------------
// Wave per node, 4 waves per 256-thr block -> 8 waves/SIMD residency.
// Softmax-aggregation without max pass (shift-invariant; |t*x| <= ~8 fp32-safe).
// Scalarized loop control (readfirstlane) so gathers issue back-to-back.
// C_IN==64: float2 gathers — lower 32 lanes cover edge 2k, upper edge 2k+1,
//   each lane holds 2 channels; halves combined via shfl_xor(32), then
//   bpermute reshuffle back to lane-per-channel. Halves gather instructions.
// C_IN==31: scalar path. Writes combined row aRows[d][0..63]:
//   C_IN==31: [aggr(31) | x(31) | 0 0],  C_IN==64: [aggr(64)].

template <int C_IN>
__global__ void __launch_bounds__(256, 8) aggr_kernel(
        const float* __restrict__ xin, const float* __restrict__ tptr,
        const int* __restrict__ row_ptr, const int* __restrict__ csr_src,
        float* __restrict__ aRows, int n) {
    int w = threadIdx.x >> 6, l = threadIdx.x & 63;
    int d = blockIdx.x * 4 + w;
    if (d >= n) return;
    float tval = tptr[0];
    int beg = __builtin_amdgcn_readfirstlane(row_ptr[d]);
    int end = __builtin_amdgcn_readfirstlane(row_ptr[d + 1]);

    if constexpr (C_IN == 64) {
        int half = l >> 5;           // 0: edge 2k, 1: edge 2k+1
        int co   = (l & 31) * 2;     // this lane's channel pair
        float2 num2 = {0.f, 0.f}, den2 = {0.f, 0.f};
        int base = beg;
        for (; base + 64 <= end; base += 64) {
            int sidx = csr_src[base + l];
            #pragma unroll
            for (int j = 0; j < 64; j += 16) {
                float2 v[8];
                #pragma unroll
                for (int p = 0; p < 8; ++p) {
                    int sa = __builtin_amdgcn_readlane(sidx, j + 2 * p);
                    int sb = __builtin_amdgcn_readlane(sidx, j + 2 * p + 1);
                    int s  = half ? sb : sa;
                    v[p] = *(const float2*)&xin[s * 64 + co];
                }
                #pragma unroll
                for (int p = 0; p < 8; ++p) {
                    float ex = __expf(tval * v[p].x);
                    float ey = __expf(tval * v[p].y);
                    den2.x += ex; den2.y += ey;
                    num2.x = fmaf(v[p].x, ex, num2.x);
                    num2.y = fmaf(v[p].y, ey, num2.y);
                }
            }
        }
        int rem = end - base;                    // scalar, 0..63
        if (rem > 0) {
            int sidx = csr_src[base + ((l < rem) ? l : 0)];
            for (int j = 0; j < rem; j += 16) {  // scalar loop, usually 1 iter
                float2 v[8];
                #pragma unroll
                for (int p = 0; p < 8; ++p) {
                    int ja = j + 2 * p;     if (ja >= rem) ja = rem - 1;
                    int jb = j + 2 * p + 1; if (jb >= rem) jb = rem - 1;
                    int sa = __builtin_amdgcn_readlane(sidx, ja);
                    int sb = __builtin_amdgcn_readlane(sidx, jb);
                    int s  = half ? sb : sa;
                    v[p] = *(const float2*)&xin[s * 64 + co];
                }
                #pragma unroll
                for (int p = 0; p < 8; ++p) {
                    float m = (j + 2 * p + half < rem) ? 1.f : 0.f;  // per-half mask
                    float ex = __expf(tval * v[p].x) * m;
                    float ey = __expf(tval * v[p].y) * m;
                    den2.x += ex; den2.y += ey;
                    num2.x = fmaf(v[p].x, ex, num2.x);
                    num2.y = fmaf(v[p].y, ey, num2.y);
                }
            }
        }
        // combine edge-halves
        num2.x += __shfl_xor(num2.x, 32);
        num2.y += __shfl_xor(num2.y, 32);
        den2.x += __shfl_xor(den2.x, 32);
        den2.y += __shfl_xor(den2.y, 32);
        // reshuffle: lane c gets (src lane c>>1, component c&1)
        float nx = __shfl(num2.x, l >> 1);
        float ny = __shfl(num2.y, l >> 1);
        float dx = __shfl(den2.x, l >> 1);
        float dy = __shfl(den2.y, l >> 1);
        float num = (l & 1) ? ny : nx;
        float den = (l & 1) ? dy : dx;
        float aggr = (end > beg) ? num / den : 0.f;
        aRows[d * 64 + l] = aggr;
    } else {
        int loff = (l < C_IN) ? l : 0;
        float xr = xin[d * C_IN + loff];
        float den = 0.f, num = 0.f;
        int base = beg;
        for (; base + 64 <= end; base += 64) {
            int sidx = csr_src[base + l];
            #pragma unroll
            for (int j = 0; j < 64; j += 16) {
                float v[16];
                #pragma unroll
                for (int i = 0; i < 16; ++i) {
                    int s = __builtin_amdgcn_readlane(sidx, j + i);
                    v[i] = xin[s * C_IN + loff];
                }
                #pragma unroll
                for (int i = 0; i < 16; ++i) {
                    float e = __expf(tval * v[i]);
                    den += e;
                    num = fmaf(v[i], e, num);
                }
            }
        }
        int rem = end - base;                      // scalar, 0..63
        if (rem > 0) {
            int sidx = csr_src[base + ((l < rem) ? l : 0)];
            for (int j = 0; j < rem; j += 16) {    // scalar loop, usually 1 iter
                float v[16];
                #pragma unroll
                for (int i = 0; i < 16; ++i) {
                    int jj = j + i;
                    if (jj >= rem) jj = rem - 1;   // scalar clamp (safe dup)
                    int s = __builtin_amdgcn_readlane(sidx, jj);
                    v[i] = xin[s * C_IN + loff];
                }
                #pragma unroll
                for (int i = 0; i < 16; ++i) {
                    float m = (j + i < rem) ? 1.f : 0.f;   // wave-uniform mask
                    float e = __expf(tval * v[i]) * m;
                    den += e;
                    num = fmaf(v[i], e, num);
                }
            }
        }
        float aggr = (end > beg) ? num / den : 0.f;
        float xs = __shfl(xr, (l - C_IN) & 63);   // lane l gets x-chan (l-31)
        float av = (l < C_IN) ? aggr : ((l < 2 * C_IN) ? xs : 0.f);
        aRows[d * 64 + l] = av;
    }
}

// ---------------- transform kernel (tiled matmul + norm + readout) ----------------
// Block = 1024 thr = 16 waves, 64 nodes/block. LDS: combined weights (K_TOT x 64)
// + 64 A-rows. Wave w computes full-K for nodes w*4..w*4+3.
// K-loop unroll capped at 2: full unroll spilled ~1.5 GB to scratch under the
// 64-VGPR cap from __launch_bounds__(1024,8) (round 6: 832 us, VALUBusy 2%).

template <int C_IN>
__global__ void __launch_bounds__(1024, 8) transform_kernel(
        const float* __restrict__ aRows, const float* __restrict__ xprev,
        const int* __restrict__ batch,
        const float* __restrict__ Wr, const float* __restrict__ br,
        const float* __restrict__ Ws,
        float* __restrict__ yout, float* __restrict__ hmax, int n) {
    constexpr int K_TOT = (C_IN == 64) ? 128 : 64;
    constexpr int K4    = K_TOT / 4;

    __shared__ float wLDS[K4 * 256];      // [k4][lane][4] : W[k][l]
    __shared__ float aLDS[64 * K_TOT];    // A[node][k]

    int tid = threadIdx.x;
    int w = tid >> 6, l = tid & 63;
    int nb = blockIdx.x * 64;

    // stage combined transposed weights, destination-ordered (conflict-free)
    for (int idx = tid; idx < K4 * 256; idx += 1024) {
        int k4 = idx >> 8;
        int ll = (idx >> 2) & 63;
        int k  = k4 * 4 + (idx & 3);
        float val;
        if (C_IN == 64) {
            val = (k < 64) ? Wr[ll * 64 + k] : Ws[ll * 64 + (k - 64)];
        } else {
            val = (k < C_IN) ? Wr[ll * C_IN + k]
                : (k < 2 * C_IN) ? Ws[ll * C_IN + (k - C_IN)] : 0.f;
        }
        wLDS[idx] = val;
    }
    // stage A rows (coalesced global reads, destination-ordered LDS writes)
    for (int idx = tid; idx < 64 * K_TOT; idx += 1024) {
        int j = idx / K_TOT, k = idx % K_TOT;
        int node = nb + j;
        if (node >= n) node = n - 1;
        float val;
        if (C_IN == 64) {
            val = (k < 64) ? aRows[node * 64 + k] : xprev[node * 64 + (k - 64)];
        } else {
            val = aRows[node * 64 + k];
        }
        aLDS[idx] = val;
    }
    __syncthreads();

    int n0 = w * 4;
    float acc0 = 0.f, acc1 = 0.f, acc2 = 0.f, acc3 = 0.f;
    #pragma unroll 2
    for (int k4 = 0; k4 < K4; ++k4) {
        float4 w4 = *(const float4*)&wLDS[k4 * 256 + l * 4];
        float4 a0 = *(const float4*)&aLDS[(n0 + 0) * K_TOT + k4 * 4];
        float4 a1 = *(const float4*)&aLDS[(n0 + 1) * K_TOT + k4 * 4];
        float4 a2 = *(const float4*)&aLDS[(n0 + 2) * K_TOT + k4 * 4];
        float4 a3 = *(const float4*)&aLDS[(n0 + 3) * K_TOT + k4 * 4];
        acc0 = fmaf(a0.x, w4.x, acc0); acc0 = fmaf(a0.y, w4.y, acc0);
        acc0 = fmaf(a0.z, w4.z, acc0); acc0 = fmaf(a0.w, w4.w, acc0);
        acc1 = fmaf(a1.x, w4.x, acc1); acc1 = fmaf(a1.y, w4.y, acc1);
        acc1 = fmaf(a1.z, w4.z, acc1); acc1 = fmaf(a1.w, w4.w, acc1);
        acc2 = fmaf(a2.x, w4.x, acc2); acc2 = fmaf(a2.y, w4.y, acc2);
        acc2 = fmaf(a2.z, w4.z, acc2); acc2 = fmaf(a2.w, w4.w, acc2);
        acc3 = fmaf(a3.x, w4.x, acc3); acc3 = fmaf(a3.y, w4.y, acc3);
        acc3 = fmaf(a3.z, w4.z, acc3); acc3 = fmaf(a3.w, w4.w, acc3);
    }

    float bias = br[l];
    float accs[4] = {acc0, acc1, acc2, acc3};
    #pragma unroll
    for (int j = 0; j < 4; ++j) {
        int d = nb + n0 + j;
        if (d < n) {
            float acc = accs[j] + bias;
            float s = acc;
            for (int off = 32; off > 0; off >>= 1) s += __shfl_xor(s, off);
            float mu = s * (1.0f / 64.0f);
            float dc = acc - mu;
            float s2 = dc * dc;
            for (int off = 32; off > 0; off >>= 1) s2 += __shfl_xor(s2, off);
            float var = s2 * (1.0f / 64.0f);
            float y = dc * rsqrtf(var + 1e-5f);
            y = fmaxf(y, 0.f);
            yout[d * 64 + l] = y;
            int g = batch[d];
            // y >= 0 and hmax zero-initialized: int-punned atomicMax order-correct
            atomicMax((int*)&hmax[g * 64 + l], __float_as_int(y));
        }
    }
}

// ---------------- MLP head ----------------

__global__ void mlp_kernel(const float* __restrict__ h,  // [3][G][64]
                           const float* __restrict__ Wl1, const float* __restrict__ bl1,
                           const float* __restrict__ Wl2, const float* __restrict__ bl2,
                           float* __restrict__ out) {
    __shared__ float hrow[192];
    __shared__ float z1[128];
    __shared__ float z2[32];
    __shared__ float snorm;
    int g = blockIdx.x, tid = threadIdx.x;  // 128 threads
    if (tid < 64) {
        hrow[tid]       = h[0 * N_GRAPHS * 64 + g * 64 + tid];
        hrow[64 + tid]  = h[1 * N_GRAPHS * 64 + g * 64 + tid];
        hrow[128 + tid] = h[2 * N_GRAPHS * 64 + g * 64 + tid];
    }
    __syncthreads();
    float acc = bl1[tid];
    #pragma unroll 8
    for (int c = 0; c < 192; ++c) acc = fmaf(hrow[c], Wl1[tid * 192 + c], acc);
    z1[tid] = fmaxf(acc, 0.f);
    __syncthreads();
    if (tid < 32) {
        float a2 = bl2[tid];
        #pragma unroll 8
        for (int c = 0; c < 128; ++c) a2 = fmaf(z1[c], Wl2[tid * 128 + c], a2);
        z2[tid] = a2;
    }
    __syncthreads();
    if (tid == 0) {
        float ss = 0.f;
        for (int i = 0; i < 32; ++i) ss += z2[i] * z2[i];
        snorm = fmaxf(sqrtf(ss), 1e-12f);
    }
    __syncthreads();
    if (tid < 32) out[g * 32 + tid] = z2[tid] / snorm;
}

// ---------------- launch ----------------

extern "C" void kernel_launch(void* const* d_in, const int* in_sizes, int n_in,
                              void* d_out, int out_size, void* d_ws, size_t ws_size,
                              hipStream_t stream) {
    const float* x   = (const float*)d_in[0];
    const int* eidx  = (const int*)d_in[1];
    const int* batch = (const int*)d_in[2];
    const float* t   = (const float*)d_in[3];
    const float* W1r = (const float*)d_in[4];
    const float* b1  = (const float*)d_in[5];
    const float* W1s = (const float*)d_in[6];
    const float* W2r = (const float*)d_in[7];
    const float* b2  = (const float*)d_in[8];
    const float* W2s = (const float*)d_in[9];
    const float* W3r = (const float*)d_in[10];
    const float* b3  = (const float*)d_in[11];
    const float* W3s = (const float*)d_in[12];
    const float* Wl1 = (const float*)d_in[13];
    const float* bl1 = (const float*)d_in[14];
    const float* Wl2 = (const float*)d_in[15];
    const float* bl2 = (const float*)d_in[16];
    float* out = (float*)d_out;

    const int nE = in_sizes[1] / 2;
    const int nN = in_sizes[2];
    const int* src = eidx;
    const int* dst = eidx + nE;

    char* ws = (char*)d_ws;
    size_t off = 0;
    auto alloc = [&](size_t bytes) {
        char* p = ws + off;
        off = (off + bytes + 255) & ~(size_t)255;
        return p;
    };
    int*   counts  = (int*)alloc((size_t)nN * 4);
    int*   row_ptr = (int*)alloc((size_t)(nN + 1) * 4);
    int*   cursor  = (int*)alloc((size_t)(nN + 1) * 4);
    int*   blk     = (int*)alloc(256 * 4);
    int*   csr_src = (int*)alloc((size_t)nE * 4);
    float* aRows   = (float*)alloc((size_t)nN * 64 * 4);
    float* yA      = (float*)alloc((size_t)nN * 64 * 4);
    float* yB      = (float*)alloc((size_t)nN * 64 * 4);
    float* h       = (float*)alloc((size_t)3 * N_GRAPHS * 64 * 4);

    const int nbE = (nE + 255) / 256;
    const int nbN = (nN + 255) / 256;

    hipMemsetAsync(counts, 0, (size_t)nN * 4, stream);
    hist_kernel<<<nbE, 256, 0, stream>>>(dst, counts, nE);
    scan_blocks_kernel<<<nbN, 256, 0, stream>>>(counts, row_ptr, blk, nN);
    scan_partials_kernel<<<1, 256, 0, stream>>>(blk, nbN);
    scan_add_kernel<<<nbN, 256, 0, stream>>>(row_ptr, blk, cursor, nN);
    scatter_kernel<<<nbE, 256, 0, stream>>>(src, dst, cursor, csr_src, nE);
    hipMemsetAsync(h, 0, (size_t)3 * N_GRAPHS * 64 * 4, stream);

    const int nbA = (nN + 3) / 4;
    const int nbT = (nN + 63) / 64;

    aggr_kernel<IN_CH><<<nbA, 256, 0, stream>>>(x, t, row_ptr, csr_src, aRows, nN);
    transform_kernel<IN_CH><<<nbT, 1024, 0, stream>>>(aRows, nullptr, batch,
                                                      W1r, b1, W1s, yA, h + 0 * N_GRAPHS * 64, nN);
    aggr_kernel<HID><<<nbA, 256, 0, stream>>>(yA, t, row_ptr, csr_src, aRows, nN);
    transform_kernel<HID><<<nbT, 1024, 0, stream>>>(aRows, yA, batch,
                                                    W2r, b2, W2s, yB, h + 1 * N_GRAPHS * 64, nN);
    aggr_kernel<HID><<<nbA, 256, 0, stream>>>(yB, t, row_ptr, csr_src, aRows, nN);
    transform_kernel<HID><<<nbT, 1024, 0, stream>>>(aRows, yB, batch,
                                                    W3r, b3, W3s, yA, h + 2 * N_GRAPHS * 64, nN);
    mlp_kernel<<<N_GRAPHS, 128, 0, stream>>>(h, Wl1, bl1, Wl2, bl2, out);
}

// Round 9
// 345.461 us; speedup vs baseline: 1.1438x; 1.1438x over previous
//
#include <hip/hip_runtime.h>

#define N_NODES 50000
#define N_EDGES 800000
#define N_GRAPHS 128
#define IN_CH 31
#define HID 64

// ---------------- CSR build: two-level counting sort ----------------
// Round 8 lesson: random 4B scatters cost 64B HBM lines each (WRITE_SIZE
// 52 MB for 3.2 MB logical, ~1.1 TB/s). Fix locality, not parallelism:
// bucket edges by dst>>7 (128-node ranges), then build CSR per bucket in a
// contiguous ~8KB window.

#define BKT_SHIFT 7
#define BKT_MAX 512     // >= nb = ceil(50000/128) = 391
#define CHUNK 8192      // edges per block in bucket_hist / bucket_scatter

__global__ void bucket_hist_kernel(const int* __restrict__ dst,
                                   int* __restrict__ bucket_cnt, int e, int nb) {
    __shared__ int bins[BKT_MAX];
    int tid = threadIdx.x;
    int i0 = blockIdx.x * CHUNK;
    int i1 = i0 + CHUNK; if (i1 > e) i1 = e;
    for (int k = tid; k < nb; k += 256) bins[k] = 0;
    __syncthreads();
    for (int j = i0 + tid; j < i1; j += 256)
        atomicAdd(&bins[dst[j] >> BKT_SHIFT], 1);
    __syncthreads();
    for (int k = tid; k < nb; k += 256)
        if (bins[k]) atomicAdd(&bucket_cnt[k], bins[k]);
}

// single block of 512: exclusive scan of nb bucket counts -> off & cur
__global__ void bucket_scan_kernel(const int* __restrict__ bucket_cnt,
                                   int* __restrict__ bucket_off,
                                   int* __restrict__ bucket_cur,
                                   int* __restrict__ row_ptr, int nb, int nN, int e) {
    __shared__ int s[512];
    int tid = threadIdx.x;
    int v = (tid < nb) ? bucket_cnt[tid] : 0;
    s[tid] = v;
    __syncthreads();
    for (int off = 1; off < 512; off <<= 1) {
        int u = (tid >= off) ? s[tid - off] : 0;
        __syncthreads();
        s[tid] += u;
        __syncthreads();
    }
    if (tid < nb) {
        int excl = s[tid] - v;
        bucket_off[tid] = excl;
        bucket_cur[tid] = excl;
    }
    if (tid == 0) {
        bucket_off[nb] = e;
        row_ptr[nN] = e;
    }
}

__global__ void bucket_scatter_kernel(const int* __restrict__ src,
                                      const int* __restrict__ dst,
                                      int* __restrict__ bucket_cur,
                                      int2* __restrict__ ebuf, int e, int nb) {
    __shared__ int bins[BKT_MAX];
    __shared__ int base[BKT_MAX];
    __shared__ int lcur[BKT_MAX];
    int tid = threadIdx.x;
    int i0 = blockIdx.x * CHUNK;
    int i1 = i0 + CHUNK; if (i1 > e) i1 = e;
    for (int k = tid; k < nb; k += 256) { bins[k] = 0; lcur[k] = 0; }
    __syncthreads();
    for (int j = i0 + tid; j < i1; j += 256)
        atomicAdd(&bins[dst[j] >> BKT_SHIFT], 1);
    __syncthreads();
    for (int k = tid; k < nb; k += 256)
        if (bins[k]) base[k] = atomicAdd(&bucket_cur[k], bins[k]);
    __syncthreads();
    for (int j = i0 + tid; j < i1; j += 256) {
        int ss = src[j], dd = dst[j];
        int b = dd >> BKT_SHIFT;
        int p = atomicAdd(&lcur[b], 1);
        ebuf[base[b] + p] = make_int2(ss, dd);
    }
}

// one block per bucket: per-node hist + scan -> row_ptr, then CSR scatter
// into the bucket's contiguous csr_src window (L2-resident, full-line fills).
__global__ void bucket_csr_kernel(const int2* __restrict__ ebuf,
                                  const int* __restrict__ bucket_off,
                                  int* __restrict__ row_ptr,
                                  int* __restrict__ csr_src, int nN) {
    __shared__ int nh[128];
    __shared__ int s[128];
    __shared__ int ncur[128];
    int tid = threadIdx.x;
    int b = blockIdx.x;
    int boff = bucket_off[b], bend = bucket_off[b + 1];
    int node0 = b << BKT_SHIFT;
    if (tid < 128) nh[tid] = 0;
    __syncthreads();
    for (int j = boff + tid; j < bend; j += 256)
        atomicAdd(&nh[ebuf[j].y - node0], 1);
    __syncthreads();
    int v = (tid < 128) ? nh[tid] : 0;
    if (tid < 128) s[tid] = v;
    __syncthreads();
    for (int off = 1; off < 128; off <<= 1) {
        int u = (tid < 128 && tid >= off) ? s[tid - off] : 0;
        __syncthreads();
        if (tid < 128) s[tid] += u;
        __syncthreads();
    }
    if (tid < 128 && node0 + tid < nN) {
        int excl = boff + s[tid] - v;
        row_ptr[node0 + tid] = excl;
        ncur[tid] = excl;
    }
    __syncthreads();
    for (int j = boff + tid; j < bend; j += 256) {
        int2 ed = ebuf[j];
        int pos = atomicAdd(&ncur[ed.y - node0], 1);
        csr_src[pos] = ed.x;
    }
}

// ---------------- aggregation kernel (no LDS, no barriers) ----------------
// Wave per node, 4 waves per 256-thr block -> 8 waves/SIMD residency.
// Softmax-aggregation without max pass (shift-invariant; |t*x| <= ~8 fp32-safe).
// Scalarized loop control (readfirstlane) so gathers issue back-to-back.
// C_IN==64: float2 gathers — lower 32 lanes cover edge 2k, upper edge 2k+1.
// C_IN==31: scalar path. Writes combined row aRows[d][0..63]:
//   C_IN==31: [aggr(31) | x(31) | 0 0],  C_IN==64: [aggr(64)].

template <int C_IN>
__global__ void __launch_bounds__(256, 8) aggr_kernel(
        const float* __restrict__ xin, const float* __restrict__ tptr,
        const int* __restrict__ row_ptr, const int* __restrict__ csr_src,
        float* __restrict__ aRows, int n) {
    int w = threadIdx.x >> 6, l = threadIdx.x & 63;
    int d = blockIdx.x * 4 + w;
    if (d >= n) return;
    float tval = tptr[0];
    int beg = __builtin_amdgcn_readfirstlane(row_ptr[d]);
    int end = __builtin_amdgcn_readfirstlane(row_ptr[d + 1]);

    if constexpr (C_IN == 64) {
        int half = l >> 5;           // 0: edge 2k, 1: edge 2k+1
        int co   = (l & 31) * 2;     // this lane's channel pair
        float2 num2 = {0.f, 0.f}, den2 = {0.f, 0.f};
        int base = beg;
        for (; base + 64 <= end; base += 64) {
            int sidx = csr_src[base + l];
            #pragma unroll
            for (int j = 0; j < 64; j += 16) {
                float2 v[8];
                #pragma unroll
                for (int p = 0; p < 8; ++p) {
                    int sa = __builtin_amdgcn_readlane(sidx, j + 2 * p);
                    int sb = __builtin_amdgcn_readlane(sidx, j + 2 * p + 1);
                    int s  = half ? sb : sa;
                    v[p] = *(const float2*)&xin[s * 64 + co];
                }
                #pragma unroll
                for (int p = 0; p < 8; ++p) {
                    float ex = __expf(tval * v[p].x);
                    float ey = __expf(tval * v[p].y);
                    den2.x += ex; den2.y += ey;
                    num2.x = fmaf(v[p].x, ex, num2.x);
                    num2.y = fmaf(v[p].y, ey, num2.y);
                }
            }
        }
        int rem = end - base;                    // scalar, 0..63
        if (rem > 0) {
            int sidx = csr_src[base + ((l < rem) ? l : 0)];
            for (int j = 0; j < rem; j += 16) {  // scalar loop, usually 1 iter
                float2 v[8];
                #pragma unroll
                for (int p = 0; p < 8; ++p) {
                    int ja = j + 2 * p;     if (ja >= rem) ja = rem - 1;
                    int jb = j + 2 * p + 1; if (jb >= rem) jb = rem - 1;
                    int sa = __builtin_amdgcn_readlane(sidx, ja);
                    int sb = __builtin_amdgcn_readlane(sidx, jb);
                    int s  = half ? sb : sa;
                    v[p] = *(const float2*)&xin[s * 64 + co];
                }
                #pragma unroll
                for (int p = 0; p < 8; ++p) {
                    float m = (j + 2 * p + half < rem) ? 1.f : 0.f;  // per-half mask
                    float ex = __expf(tval * v[p].x) * m;
                    float ey = __expf(tval * v[p].y) * m;
                    den2.x += ex; den2.y += ey;
                    num2.x = fmaf(v[p].x, ex, num2.x);
                    num2.y = fmaf(v[p].y, ey, num2.y);
                }
            }
        }
        // combine edge-halves
        num2.x += __shfl_xor(num2.x, 32);
        num2.y += __shfl_xor(num2.y, 32);
        den2.x += __shfl_xor(den2.x, 32);
        den2.y += __shfl_xor(den2.y, 32);
        // reshuffle: lane c gets (src lane c>>1, component c&1)
        float nx = __shfl(num2.x, l >> 1);
        float ny = __shfl(num2.y, l >> 1);
        float dx = __shfl(den2.x, l >> 1);
        float dy = __shfl(den2.y, l >> 1);
        float num = (l & 1) ? ny : nx;
        float den = (l & 1) ? dy : dx;
        float aggr = (end > beg) ? num / den : 0.f;
        aRows[d * 64 + l] = aggr;
    } else {
        int loff = (l < C_IN) ? l : 0;
        float xr = xin[d * C_IN + loff];
        float den = 0.f, num = 0.f;
        int base = beg;
        for (; base + 64 <= end; base += 64) {
            int sidx = csr_src[base + l];
            #pragma unroll
            for (int j = 0; j < 64; j += 16) {
                float v[16];
                #pragma unroll
                for (int i = 0; i < 16; ++i) {
                    int s = __builtin_amdgcn_readlane(sidx, j + i);
                    v[i] = xin[s * C_IN + loff];
                }
                #pragma unroll
                for (int i = 0; i < 16; ++i) {
                    float e = __expf(tval * v[i]);
                    den += e;
                    num = fmaf(v[i], e, num);
                }
            }
        }
        int rem = end - base;                      // scalar, 0..63
        if (rem > 0) {
            int sidx = csr_src[base + ((l < rem) ? l : 0)];
            for (int j = 0; j < rem; j += 16) {    // scalar loop, usually 1 iter
                float v[16];
                #pragma unroll
                for (int i = 0; i < 16; ++i) {
                    int jj = j + i;
                    if (jj >= rem) jj = rem - 1;   // scalar clamp (safe dup)
                    int s = __builtin_amdgcn_readlane(sidx, jj);
                    v[i] = xin[s * C_IN + loff];
                }
                #pragma unroll
                for (int i = 0; i < 16; ++i) {
                    float m = (j + i < rem) ? 1.f : 0.f;   // wave-uniform mask
                    float e = __expf(tval * v[i]) * m;
                    den += e;
                    num = fmaf(v[i], e, num);
                }
            }
        }
        float aggr = (end > beg) ? num / den : 0.f;
        float xs = __shfl(xr, (l - C_IN) & 63);   // lane l gets x-chan (l-31)
        float av = (l < C_IN) ? aggr : ((l < 2 * C_IN) ? xs : 0.f);
        aRows[d * 64 + l] = av;
    }
}

// ---------------- transform kernel (tiled matmul + norm + readout) ----------------
// Block = 1024 thr = 16 waves, 64 nodes/block. LDS: combined weights (K_TOT x 64)
// + 64 A-rows. Wave w computes full-K for nodes w*4..w*4+3.
// K-loop unroll capped at 2: full unroll spilled ~1.5 GB to scratch under the
// 64-VGPR cap from __launch_bounds__(1024,8) (round 6: 832 us, VALUBusy 2%).

template <int C_IN>
__global__ void __launch_bounds__(1024, 8) transform_kernel(
        const float* __restrict__ aRows, const float* __restrict__ xprev,
        const int* __restrict__ batch,
        const float* __restrict__ Wr, const float* __restrict__ br,
        const float* __restrict__ Ws,
        float* __restrict__ yout, float* __restrict__ hmax, int n) {
    constexpr int K_TOT = (C_IN == 64) ? 128 : 64;
    constexpr int K4    = K_TOT / 4;

    __shared__ float wLDS[K4 * 256];      // [k4][lane][4] : W[k][l]
    __shared__ float aLDS[64 * K_TOT];    // A[node][k]

    int tid = threadIdx.x;
    int w = tid >> 6, l = tid & 63;
    int nb = blockIdx.x * 64;

    // stage combined transposed weights, destination-ordered (conflict-free)
    for (int idx = tid; idx < K4 * 256; idx += 1024) {
        int k4 = idx >> 8;
        int ll = (idx >> 2) & 63;
        int k  = k4 * 4 + (idx & 3);
        float val;
        if (C_IN == 64) {
            val = (k < 64) ? Wr[ll * 64 + k] : Ws[ll * 64 + (k - 64)];
        } else {
            val = (k < C_IN) ? Wr[ll * C_IN + k]
                : (k < 2 * C_IN) ? Ws[ll * C_IN + (k - C_IN)] : 0.f;
        }
        wLDS[idx] = val;
    }
    // stage A rows (coalesced global reads, destination-ordered LDS writes)
    for (int idx = tid; idx < 64 * K_TOT; idx += 1024) {
        int j = idx / K_TOT, k = idx % K_TOT;
        int node = nb + j;
        if (node >= n) node = n - 1;
        float val;
        if (C_IN == 64) {
            val = (k < 64) ? aRows[node * 64 + k] : xprev[node * 64 + (k - 64)];
        } else {
            val = aRows[node * 64 + k];
        }
        aLDS[idx] = val;
    }
    __syncthreads();

    int n0 = w * 4;
    float acc0 = 0.f, acc1 = 0.f, acc2 = 0.f, acc3 = 0.f;
    #pragma unroll 2
    for (int k4 = 0; k4 < K4; ++k4) {
        float4 w4 = *(const float4*)&wLDS[k4 * 256 + l * 4];
        float4 a0 = *(const float4*)&aLDS[(n0 + 0) * K_TOT + k4 * 4];
        float4 a1 = *(const float4*)&aLDS[(n0 + 1) * K_TOT + k4 * 4];
        float4 a2 = *(const float4*)&aLDS[(n0 + 2) * K_TOT + k4 * 4];
        float4 a3 = *(const float4*)&aLDS[(n0 + 3) * K_TOT + k4 * 4];
        acc0 = fmaf(a0.x, w4.x, acc0); acc0 = fmaf(a0.y, w4.y, acc0);
        acc0 = fmaf(a0.z, w4.z, acc0); acc0 = fmaf(a0.w, w4.w, acc0);
        acc1 = fmaf(a1.x, w4.x, acc1); acc1 = fmaf(a1.y, w4.y, acc1);
        acc1 = fmaf(a1.z, w4.z, acc1); acc1 = fmaf(a1.w, w4.w, acc1);
        acc2 = fmaf(a2.x, w4.x, acc2); acc2 = fmaf(a2.y, w4.y, acc2);
        acc2 = fmaf(a2.z, w4.z, acc2); acc2 = fmaf(a2.w, w4.w, acc2);
        acc3 = fmaf(a3.x, w4.x, acc3); acc3 = fmaf(a3.y, w4.y, acc3);
        acc3 = fmaf(a3.z, w4.z, acc3); acc3 = fmaf(a3.w, w4.w, acc3);
    }

    float bias = br[l];
    float accs[4] = {acc0, acc1, acc2, acc3};
    #pragma unroll
    for (int j = 0; j < 4; ++j) {
        int d = nb + n0 + j;
        if (d < n) {
            float acc = accs[j] + bias;
            float s = acc;
            for (int off = 32; off > 0; off >>= 1) s += __shfl_xor(s, off);
            float mu = s * (1.0f / 64.0f);
            float dc = acc - mu;
            float s2 = dc * dc;
            for (int off = 32; off > 0; off >>= 1) s2 += __shfl_xor(s2, off);
            float var = s2 * (1.0f / 64.0f);
            float y = dc * rsqrtf(var + 1e-5f);
            y = fmaxf(y, 0.f);
            yout[d * 64 + l] = y;
            int g = batch[d];
            // y >= 0 and hmax zero-initialized: int-punned atomicMax order-correct
            atomicMax((int*)&hmax[g * 64 + l], __float_as_int(y));
        }
    }
}

// ---------------- MLP head ----------------

__global__ void mlp_kernel(const float* __restrict__ h,  // [3][G][64]
                           const float* __restrict__ Wl1, const float* __restrict__ bl1,
                           const float* __restrict__ Wl2, const float* __restrict__ bl2,
                           float* __restrict__ out) {
    __shared__ float hrow[192];
    __shared__ float z1[128];
    __shared__ float z2[32];
    __shared__ float snorm;
    int g = blockIdx.x, tid = threadIdx.x;  // 128 threads
    if (tid < 64) {
        hrow[tid]       = h[0 * N_GRAPHS * 64 + g * 64 + tid];
        hrow[64 + tid]  = h[1 * N_GRAPHS * 64 + g * 64 + tid];
        hrow[128 + tid] = h[2 * N_GRAPHS * 64 + g * 64 + tid];
    }
    __syncthreads();
    float acc = bl1[tid];
    #pragma unroll 8
    for (int c = 0; c < 192; ++c) acc = fmaf(hrow[c], Wl1[tid * 192 + c], acc);
    z1[tid] = fmaxf(acc, 0.f);
    __syncthreads();
    if (tid < 32) {
        float a2 = bl2[tid];
        #pragma unroll 8
        for (int c = 0; c < 128; ++c) a2 = fmaf(z1[c], Wl2[tid * 128 + c], a2);
        z2[tid] = a2;
    }
    __syncthreads();
    if (tid == 0) {
        float ss = 0.f;
        for (int i = 0; i < 32; ++i) ss += z2[i] * z2[i];
        snorm = fmaxf(sqrtf(ss), 1e-12f);
    }
    __syncthreads();
    if (tid < 32) out[g * 32 + tid] = z2[tid] / snorm;
}

// ---------------- launch ----------------

extern "C" void kernel_launch(void* const* d_in, const int* in_sizes, int n_in,
                              void* d_out, int out_size, void* d_ws, size_t ws_size,
                              hipStream_t stream) {
    const float* x   = (const float*)d_in[0];
    const int* eidx  = (const int*)d_in[1];
    const int* batch = (const int*)d_in[2];
    const float* t   = (const float*)d_in[3];
    const float* W1r = (const float*)d_in[4];
    const float* b1  = (const float*)d_in[5];
    const float* W1s = (const float*)d_in[6];
    const float* W2r = (const float*)d_in[7];
    const float* b2  = (const float*)d_in[8];
    const float* W2s = (const float*)d_in[9];
    const float* W3r = (const float*)d_in[10];
    const float* b3  = (const float*)d_in[11];
    const float* W3s = (const float*)d_in[12];
    const float* Wl1 = (const float*)d_in[13];
    const float* bl1 = (const float*)d_in[14];
    const float* Wl2 = (const float*)d_in[15];
    const float* bl2 = (const float*)d_in[16];
    float* out = (float*)d_out;

    const int nE = in_sizes[1] / 2;
    const int nN = in_sizes[2];
    const int* src = eidx;
    const int* dst = eidx + nE;
    const int nb = (nN + 127) >> BKT_SHIFT;   // buckets of 128 nodes

    char* ws = (char*)d_ws;
    size_t off = 0;
    auto alloc = [&](size_t bytes) {
        char* p = ws + off;
        off = (off + bytes + 255) & ~(size_t)255;
        return p;
    };
    // bucket_cnt and h adjacent -> single zeroing memset
    int*   bucket_cnt = (int*)alloc((size_t)(nb + 1) * 4);
    float* h          = (float*)alloc((size_t)3 * N_GRAPHS * 64 * 4);
    int*   bucket_off = (int*)alloc((size_t)(nb + 1) * 4);
    int*   bucket_cur = (int*)alloc((size_t)(nb + 1) * 4);
    int*   row_ptr    = (int*)alloc((size_t)(nN + 1) * 4);
    int2*  ebuf       = (int2*)alloc((size_t)nE * 8);
    int*   csr_src    = (int*)alloc((size_t)nE * 4);
    float* aRows      = (float*)alloc((size_t)nN * 64 * 4);
    float* yA         = (float*)alloc((size_t)nN * 64 * 4);
    float* yB         = (float*)alloc((size_t)nN * 64 * 4);

    const int nbChunk = (nE + CHUNK - 1) / CHUNK;

    // one memset covers bucket_cnt + h (contiguous in ws)
    hipMemsetAsync(bucket_cnt, 0,
                   (char*)(h + 3 * N_GRAPHS * 64) - (char*)bucket_cnt, stream);
    bucket_hist_kernel<<<nbChunk, 256, 0, stream>>>(dst, bucket_cnt, nE, nb);
    bucket_scan_kernel<<<1, 512, 0, stream>>>(bucket_cnt, bucket_off, bucket_cur,
                                              row_ptr, nb, nN, nE);
    bucket_scatter_kernel<<<nbChunk, 256, 0, stream>>>(src, dst, bucket_cur, ebuf, nE, nb);
    bucket_csr_kernel<<<nb, 256, 0, stream>>>(ebuf, bucket_off, row_ptr, csr_src, nN);

    const int nbA = (nN + 3) / 4;
    const int nbT = (nN + 63) / 64;

    aggr_kernel<IN_CH><<<nbA, 256, 0, stream>>>(x, t, row_ptr, csr_src, aRows, nN);
    transform_kernel<IN_CH><<<nbT, 1024, 0, stream>>>(aRows, nullptr, batch,
                                                      W1r, b1, W1s, yA, h + 0 * N_GRAPHS * 64, nN);
    aggr_kernel<HID><<<nbA, 256, 0, stream>>>(yA, t, row_ptr, csr_src, aRows, nN);
    transform_kernel<HID><<<nbT, 1024, 0, stream>>>(aRows, yA, batch,
                                                    W2r, b2, W2s, yB, h + 1 * N_GRAPHS * 64, nN);
    aggr_kernel<HID><<<nbA, 256, 0, stream>>>(yB, t, row_ptr, csr_src, aRows, nN);
    transform_kernel<HID><<<nbT, 1024, 0, stream>>>(aRows, yB, batch,
                                                    W3r, b3, W3s, yA, h + 2 * N_GRAPHS * 64, nN);
    mlp_kernel<<<N_GRAPHS, 128, 0, stream>>>(h, Wl1, bl1, Wl2, bl2, out);
}

// Round 10
// 332.611 us; speedup vs baseline: 1.1880x; 1.0386x over previous
//
#include <hip/hip_runtime.h>

#define N_NODES 50000
#define N_EDGES 800000
#define N_GRAPHS 128
#define IN_CH 31
#define HID 64

typedef __attribute__((ext_vector_type(8))) short short8;
typedef __attribute__((ext_vector_type(4))) float floatx4;

__device__ inline unsigned f2bf(float f) {   // RNE fp32 -> bf16 bits
    union { float f; unsigned u; } v; v.f = f;
    unsigned r = v.u + 0x7fff + ((v.u >> 16) & 1);
    return r >> 16;
}
__device__ inline void pack4(short* p, float4 v) {  // p 8B-aligned
    unsigned lo = f2bf(v.x) | (f2bf(v.y) << 16);
    unsigned hi = f2bf(v.z) | (f2bf(v.w) << 16);
    *(uint2*)p = make_uint2(lo, hi);
}

// ---------------- CSR build: two-level counting sort ----------------
// Random 4B scatters cost 64B HBM lines each (round 8: WRITE 52 MB for
// 3.2 MB logical). Bucket edges by dst>>7, build CSR per bucket in a
// contiguous ~8KB window (L2-resident full-line fills).

#define BKT_SHIFT 7
#define BKT_MAX 512
#define CHUNK 8192

__global__ void bucket_hist_kernel(const int* __restrict__ dst,
                                   int* __restrict__ bucket_cnt, int e, int nb) {
    __shared__ int bins[BKT_MAX];
    int tid = threadIdx.x;
    int i0 = blockIdx.x * CHUNK;
    int i1 = i0 + CHUNK; if (i1 > e) i1 = e;
    for (int k = tid; k < nb; k += 256) bins[k] = 0;
    __syncthreads();
    for (int j = i0 + tid; j < i1; j += 256)
        atomicAdd(&bins[dst[j] >> BKT_SHIFT], 1);
    __syncthreads();
    for (int k = tid; k < nb; k += 256)
        if (bins[k]) atomicAdd(&bucket_cnt[k], bins[k]);
}

__global__ void bucket_scan_kernel(const int* __restrict__ bucket_cnt,
                                   int* __restrict__ bucket_off,
                                   int* __restrict__ bucket_cur,
                                   int* __restrict__ row_ptr, int nb, int nN, int e) {
    __shared__ int s[512];
    int tid = threadIdx.x;
    int v = (tid < nb) ? bucket_cnt[tid] : 0;
    s[tid] = v;
    __syncthreads();
    for (int off = 1; off < 512; off <<= 1) {
        int u = (tid >= off) ? s[tid - off] : 0;
        __syncthreads();
        s[tid] += u;
        __syncthreads();
    }
    if (tid < nb) {
        int excl = s[tid] - v;
        bucket_off[tid] = excl;
        bucket_cur[tid] = excl;
    }
    if (tid == 0) {
        bucket_off[nb] = e;
        row_ptr[nN] = e;
    }
}

__global__ void bucket_scatter_kernel(const int* __restrict__ src,
                                      const int* __restrict__ dst,
                                      int* __restrict__ bucket_cur,
                                      int2* __restrict__ ebuf, int e, int nb) {
    __shared__ int bins[BKT_MAX];
    __shared__ int base[BKT_MAX];
    __shared__ int lcur[BKT_MAX];
    int tid = threadIdx.x;
    int i0 = blockIdx.x * CHUNK;
    int i1 = i0 + CHUNK; if (i1 > e) i1 = e;
    for (int k = tid; k < nb; k += 256) { bins[k] = 0; lcur[k] = 0; }
    __syncthreads();
    for (int j = i0 + tid; j < i1; j += 256)
        atomicAdd(&bins[dst[j] >> BKT_SHIFT], 1);
    __syncthreads();
    for (int k = tid; k < nb; k += 256)
        if (bins[k]) base[k] = atomicAdd(&bucket_cur[k], bins[k]);
    __syncthreads();
    for (int j = i0 + tid; j < i1; j += 256) {
        int ss = src[j], dd = dst[j];
        int b = dd >> BKT_SHIFT;
        int p = atomicAdd(&lcur[b], 1);
        ebuf[base[b] + p] = make_int2(ss, dd);
    }
}

__global__ void bucket_csr_kernel(const int2* __restrict__ ebuf,
                                  const int* __restrict__ bucket_off,
                                  int* __restrict__ row_ptr,
                                  int* __restrict__ csr_src, int nN) {
    __shared__ int nh[128];
    __shared__ int s[128];
    __shared__ int ncur[128];
    int tid = threadIdx.x;
    int b = blockIdx.x;
    int boff = bucket_off[b], bend = bucket_off[b + 1];
    int node0 = b << BKT_SHIFT;
    if (tid < 128) nh[tid] = 0;
    __syncthreads();
    for (int j = boff + tid; j < bend; j += 256)
        atomicAdd(&nh[ebuf[j].y - node0], 1);
    __syncthreads();
    int v = (tid < 128) ? nh[tid] : 0;
    if (tid < 128) s[tid] = v;
    __syncthreads();
    for (int off = 1; off < 128; off <<= 1) {
        int u = (tid < 128 && tid >= off) ? s[tid - off] : 0;
        __syncthreads();
        if (tid < 128) s[tid] += u;
        __syncthreads();
    }
    if (tid < 128 && node0 + tid < nN) {
        int excl = boff + s[tid] - v;
        row_ptr[node0 + tid] = excl;
        ncur[tid] = excl;
    }
    __syncthreads();
    for (int j = boff + tid; j < bend; j += 256) {
        int2 ed = ebuf[j];
        int pos = atomicAdd(&ncur[ed.y - node0], 1);
        csr_src[pos] = ed.x;
    }
}

// ---------------- aggregation kernel (no LDS, no barriers) ----------------
// Wave per node. Softmax-aggregation without max pass (shift-invariant;
// |t*x| <= ~8 fp32-safe). Scalarized loop control so gathers issue
// back-to-back. Writes combined row aRows[d][0..63]:
//   C_IN==31: [aggr(31) | x(31) | 0 0],  C_IN==64: [aggr(64)].

template <int C_IN>
__global__ void __launch_bounds__(256, 8) aggr_kernel(
        const float* __restrict__ xin, const float* __restrict__ tptr,
        const int* __restrict__ row_ptr, const int* __restrict__ csr_src,
        float* __restrict__ aRows, int n) {
    int w = threadIdx.x >> 6, l = threadIdx.x & 63;
    int d = blockIdx.x * 4 + w;
    if (d >= n) return;
    float tval = tptr[0];
    int beg = __builtin_amdgcn_readfirstlane(row_ptr[d]);
    int end = __builtin_amdgcn_readfirstlane(row_ptr[d + 1]);

    if constexpr (C_IN == 64) {
        int half = l >> 5;           // 0: edge 2k, 1: edge 2k+1
        int co   = (l & 31) * 2;     // this lane's channel pair
        float2 num2 = {0.f, 0.f}, den2 = {0.f, 0.f};
        int base = beg;
        for (; base + 64 <= end; base += 64) {
            int sidx = csr_src[base + l];
            #pragma unroll
            for (int j = 0; j < 64; j += 16) {
                float2 v[8];
                #pragma unroll
                for (int p = 0; p < 8; ++p) {
                    int sa = __builtin_amdgcn_readlane(sidx, j + 2 * p);
                    int sb = __builtin_amdgcn_readlane(sidx, j + 2 * p + 1);
                    int s  = half ? sb : sa;
                    v[p] = *(const float2*)&xin[s * 64 + co];
                }
                #pragma unroll
                for (int p = 0; p < 8; ++p) {
                    float ex = __expf(tval * v[p].x);
                    float ey = __expf(tval * v[p].y);
                    den2.x += ex; den2.y += ey;
                    num2.x = fmaf(v[p].x, ex, num2.x);
                    num2.y = fmaf(v[p].y, ey, num2.y);
                }
            }
        }
        int rem = end - base;
        if (rem > 0) {
            int sidx = csr_src[base + ((l < rem) ? l : 0)];
            for (int j = 0; j < rem; j += 16) {
                float2 v[8];
                #pragma unroll
                for (int p = 0; p < 8; ++p) {
                    int ja = j + 2 * p;     if (ja >= rem) ja = rem - 1;
                    int jb = j + 2 * p + 1; if (jb >= rem) jb = rem - 1;
                    int sa = __builtin_amdgcn_readlane(sidx, ja);
                    int sb = __builtin_amdgcn_readlane(sidx, jb);
                    int s  = half ? sb : sa;
                    v[p] = *(const float2*)&xin[s * 64 + co];
                }
                #pragma unroll
                for (int p = 0; p < 8; ++p) {
                    float m = (j + 2 * p + half < rem) ? 1.f : 0.f;
                    float ex = __expf(tval * v[p].x) * m;
                    float ey = __expf(tval * v[p].y) * m;
                    den2.x += ex; den2.y += ey;
                    num2.x = fmaf(v[p].x, ex, num2.x);
                    num2.y = fmaf(v[p].y, ey, num2.y);
                }
            }
        }
        num2.x += __shfl_xor(num2.x, 32);
        num2.y += __shfl_xor(num2.y, 32);
        den2.x += __shfl_xor(den2.x, 32);
        den2.y += __shfl_xor(den2.y, 32);
        float nx = __shfl(num2.x, l >> 1);
        float ny = __shfl(num2.y, l >> 1);
        float dx = __shfl(den2.x, l >> 1);
        float dy = __shfl(den2.y, l >> 1);
        float num = (l & 1) ? ny : nx;
        float den = (l & 1) ? dy : dx;
        float aggr = (end > beg) ? num / den : 0.f;
        aRows[d * 64 + l] = aggr;
    } else {
        int loff = (l < C_IN) ? l : 0;
        float xr = xin[d * C_IN + loff];
        float den = 0.f, num = 0.f;
        int base = beg;
        for (; base + 64 <= end; base += 64) {
            int sidx = csr_src[base + l];
            #pragma unroll
            for (int j = 0; j < 64; j += 16) {
                float v[16];
                #pragma unroll
                for (int i = 0; i < 16; ++i) {
                    int s = __builtin_amdgcn_readlane(sidx, j + i);
                    v[i] = xin[s * C_IN + loff];
                }
                #pragma unroll
                for (int i = 0; i < 16; ++i) {
                    float e = __expf(tval * v[i]);
                    den += e;
                    num = fmaf(v[i], e, num);
                }
            }
        }
        int rem = end - base;
        if (rem > 0) {
            int sidx = csr_src[base + ((l < rem) ? l : 0)];
            for (int j = 0; j < rem; j += 16) {
                float v[16];
                #pragma unroll
                for (int i = 0; i < 16; ++i) {
                    int jj = j + i;
                    if (jj >= rem) jj = rem - 1;
                    int s = __builtin_amdgcn_readlane(sidx, jj);
                    v[i] = xin[s * C_IN + loff];
                }
                #pragma unroll
                for (int i = 0; i < 16; ++i) {
                    float m = (j + i < rem) ? 1.f : 0.f;
                    float e = __expf(tval * v[i]) * m;
                    den += e;
                    num = fmaf(v[i], e, num);
                }
            }
        }
        float aggr = (end > beg) ? num / den : 0.f;
        float xs = __shfl(xr, (l - C_IN) & 63);
        float av = (l < C_IN) ? aggr : ((l < 2 * C_IN) ? xs : 0.f);
        aRows[d * 64 + l] = av;
    }
}

// ---------------- MFMA transform kernel ----------------
// Y[64 nodes x 64 ch] = A[64 x K_TOT] @ W^T via mfma_f32_16x16x32_bf16.
// Round 9 analysis: fp32 scheme was LDS-issue bound (2560 ds_read_b128/block
// x 12 cyc = 39 us). MFMA needs ~80 frag reads/block. bf16 inputs, fp32 acc.
// Block = 256 thr = 4 waves; wave w: node-tile w (16 nodes) x 4 ch-tiles.
// A-frag: lane m=l&15 (node), k=(l>>4)*8+j -> ds_read_b128 from padded sA.
// B-frag: lane n=l&15 (out ch), same k -> sB rows = [Wr row | Ws row] (native
// layout!). C/D: col=lane&15, row=(lane>>4)*4+reg (m89-verified). Epilogue:
// acc -> padded sC -> per-node instnorm/ReLU/store/atomicMax (as before).

template <int C_IN>
__global__ void __launch_bounds__(256, 4) transform_kernel(
        const float* __restrict__ aRows, const float* __restrict__ xprev,
        const int* __restrict__ batch,
        const float* __restrict__ Wr, const float* __restrict__ br,
        const float* __restrict__ Ws,
        float* __restrict__ yout, float* __restrict__ hmax, int n) {
    constexpr int K_TOT = (C_IN == 64) ? 128 : 64;
    constexpr int KP    = K_TOT + 8;       // short-padded row (2-way-free banks)
    constexpr int KS    = K_TOT / 32;      // mfma k-steps

    __shared__ short sA[64 * KP];
    __shared__ short sB[64 * KP];
    __shared__ float sC[64 * 68];          // +4 pad: 2-way-free

    int tid = threadIdx.x;
    int nb = blockIdx.x * 64;

    if constexpr (C_IN == 64) {
        for (int idx = tid; idx < 64 * 32; idx += 256) {      // A: aRows|xprev
            int row = idx >> 5, c4 = idx & 31;
            int node = nb + row; if (node >= n) node = n - 1;
            float4 v = (c4 < 16) ? ((const float4*)(aRows + (size_t)node * 64))[c4]
                                 : ((const float4*)(xprev + (size_t)node * 64))[c4 - 16];
            pack4(&sA[row * KP + c4 * 4], v);
        }
        for (int idx = tid; idx < 64 * 32; idx += 256) {      // B: Wr|Ws rows
            int nr = idx >> 5, c4 = idx & 31;
            float4 v = (c4 < 16) ? ((const float4*)(Wr + nr * 64))[c4]
                                 : ((const float4*)(Ws + nr * 64))[c4 - 16];
            pack4(&sB[nr * KP + c4 * 4], v);
        }
    } else {
        for (int idx = tid; idx < 64 * 16; idx += 256) {      // A: combined aRows
            int row = idx >> 4, c4 = idx & 15;
            int node = nb + row; if (node >= n) node = n - 1;
            float4 v = ((const float4*)(aRows + (size_t)node * 64))[c4];
            pack4(&sA[row * KP + c4 * 4], v);
        }
        for (int idx = tid; idx < 64 * 64; idx += 256) {      // B scalar (31 odd)
            int nr = idx >> 6, k = idx & 63;
            float v = (k < C_IN) ? Wr[nr * C_IN + k]
                    : (k < 2 * C_IN) ? Ws[nr * C_IN + (k - C_IN)] : 0.f;
            sB[nr * KP + k] = (short)f2bf(v);
        }
    }
    __syncthreads();

    int w = tid >> 6, l = tid & 63;
    int m = l & 15;        // node (A) / out-channel (B) within tile
    int q = l >> 4;        // quad -> k-offset q*8
    floatx4 acc[4] = {{0.f,0.f,0.f,0.f},{0.f,0.f,0.f,0.f},
                      {0.f,0.f,0.f,0.f},{0.f,0.f,0.f,0.f}};
    const short* aBase = &sA[(w * 16 + m) * KP + q * 8];
    #pragma unroll 2
    for (int s = 0; s < KS; ++s) {
        short8 af = *(const short8*)(aBase + s * 32);
        #pragma unroll
        for (int t = 0; t < 4; ++t) {
            short8 bf = *(const short8*)&sB[(t * 16 + m) * KP + q * 8 + s * 32];
            acc[t] = __builtin_amdgcn_mfma_f32_16x16x32_bf16(af, bf, acc[t], 0, 0, 0);
        }
    }

    #pragma unroll
    for (int t = 0; t < 4; ++t)
        #pragma unroll
        for (int r = 0; r < 4; ++r)
            sC[(w * 16 + q * 4 + r) * 68 + t * 16 + m] = acc[t][r];
    __syncthreads();

    float bias = br[l];
    for (int i = 0; i < 16; ++i) {
        int j = w * 16 + i;
        int d = nb + j;
        if (d < n) {
            float a = sC[j * 68 + l] + bias;
            float s = a;
            for (int off = 32; off > 0; off >>= 1) s += __shfl_xor(s, off);
            float mu = s * (1.0f / 64.0f);
            float dc = a - mu;
            float s2 = dc * dc;
            for (int off = 32; off > 0; off >>= 1) s2 += __shfl_xor(s2, off);
            float var = s2 * (1.0f / 64.0f);
            float y = dc * rsqrtf(var + 1e-5f);
            y = fmaxf(y, 0.f);
            yout[(size_t)d * 64 + l] = y;
            int g = batch[d];
            // y >= 0, hmax zero-init: int-punned atomicMax order-correct
            atomicMax((int*)&hmax[g * 64 + l], __float_as_int(y));
        }
    }
}

// ---------------- MLP head ----------------

__global__ void mlp_kernel(const float* __restrict__ h,  // [3][G][64]
                           const float* __restrict__ Wl1, const float* __restrict__ bl1,
                           const float* __restrict__ Wl2, const float* __restrict__ bl2,
                           float* __restrict__ out) {
    __shared__ float hrow[192];
    __shared__ float z1[128];
    __shared__ float z2[32];
    __shared__ float snorm;
    int g = blockIdx.x, tid = threadIdx.x;  // 128 threads
    if (tid < 64) {
        hrow[tid]       = h[0 * N_GRAPHS * 64 + g * 64 + tid];
        hrow[64 + tid]  = h[1 * N_GRAPHS * 64 + g * 64 + tid];
        hrow[128 + tid] = h[2 * N_GRAPHS * 64 + g * 64 + tid];
    }
    __syncthreads();
    float acc = bl1[tid];
    #pragma unroll 8
    for (int c = 0; c < 192; ++c) acc = fmaf(hrow[c], Wl1[tid * 192 + c], acc);
    z1[tid] = fmaxf(acc, 0.f);
    __syncthreads();
    if (tid < 32) {
        float a2 = bl2[tid];
        #pragma unroll 8
        for (int c = 0; c < 128; ++c) a2 = fmaf(z1[c], Wl2[tid * 128 + c], a2);
        z2[tid] = a2;
    }
    __syncthreads();
    if (tid == 0) {
        float ss = 0.f;
        for (int i = 0; i < 32; ++i) ss += z2[i] * z2[i];
        snorm = fmaxf(sqrtf(ss), 1e-12f);
    }
    __syncthreads();
    if (tid < 32) out[g * 32 + tid] = z2[tid] / snorm;
}

// ---------------- launch ----------------

extern "C" void kernel_launch(void* const* d_in, const int* in_sizes, int n_in,
                              void* d_out, int out_size, void* d_ws, size_t ws_size,
                              hipStream_t stream) {
    const float* x   = (const float*)d_in[0];
    const int* eidx  = (const int*)d_in[1];
    const int* batch = (const int*)d_in[2];
    const float* t   = (const float*)d_in[3];
    const float* W1r = (const float*)d_in[4];
    const float* b1  = (const float*)d_in[5];
    const float* W1s = (const float*)d_in[6];
    const float* W2r = (const float*)d_in[7];
    const float* b2  = (const float*)d_in[8];
    const float* W2s = (const float*)d_in[9];
    const float* W3r = (const float*)d_in[10];
    const float* b3  = (const float*)d_in[11];
    const float* W3s = (const float*)d_in[12];
    const float* Wl1 = (const float*)d_in[13];
    const float* bl1 = (const float*)d_in[14];
    const float* Wl2 = (const float*)d_in[15];
    const float* bl2 = (const float*)d_in[16];
    float* out = (float*)d_out;

    const int nE = in_sizes[1] / 2;
    const int nN = in_sizes[2];
    const int* src = eidx;
    const int* dst = eidx + nE;
    const int nb = (nN + 127) >> BKT_SHIFT;

    char* ws = (char*)d_ws;
    size_t off = 0;
    auto alloc = [&](size_t bytes) {
        char* p = ws + off;
        off = (off + bytes + 255) & ~(size_t)255;
        return p;
    };
    int*   bucket_cnt = (int*)alloc((size_t)(nb + 1) * 4);
    float* h          = (float*)alloc((size_t)3 * N_GRAPHS * 64 * 4);
    int*   bucket_off = (int*)alloc((size_t)(nb + 1) * 4);
    int*   bucket_cur = (int*)alloc((size_t)(nb + 1) * 4);
    int*   row_ptr    = (int*)alloc((size_t)(nN + 1) * 4);
    int2*  ebuf       = (int2*)alloc((size_t)nE * 8);
    int*   csr_src    = (int*)alloc((size_t)nE * 4);
    float* aRows      = (float*)alloc((size_t)nN * 64 * 4);
    float* yA         = (float*)alloc((size_t)nN * 64 * 4);
    float* yB         = (float*)alloc((size_t)nN * 64 * 4);

    const int nbChunk = (nE + CHUNK - 1) / CHUNK;

    hipMemsetAsync(bucket_cnt, 0,
                   (char*)(h + 3 * N_GRAPHS * 64) - (char*)bucket_cnt, stream);
    bucket_hist_kernel<<<nbChunk, 256, 0, stream>>>(dst, bucket_cnt, nE, nb);
    bucket_scan_kernel<<<1, 512, 0, stream>>>(bucket_cnt, bucket_off, bucket_cur,
                                              row_ptr, nb, nN, nE);
    bucket_scatter_kernel<<<nbChunk, 256, 0, stream>>>(src, dst, bucket_cur, ebuf, nE, nb);
    bucket_csr_kernel<<<nb, 256, 0, stream>>>(ebuf, bucket_off, row_ptr, csr_src, nN);

    const int nbA = (nN + 3) / 4;
    const int nbT = (nN + 63) / 64;

    aggr_kernel<IN_CH><<<nbA, 256, 0, stream>>>(x, t, row_ptr, csr_src, aRows, nN);
    transform_kernel<IN_CH><<<nbT, 256, 0, stream>>>(aRows, nullptr, batch,
                                                     W1r, b1, W1s, yA, h + 0 * N_GRAPHS * 64, nN);
    aggr_kernel<HID><<<nbA, 256, 0, stream>>>(yA, t, row_ptr, csr_src, aRows, nN);
    transform_kernel<HID><<<nbT, 256, 0, stream>>>(aRows, yA, batch,
                                                   W2r, b2, W2s, yB, h + 1 * N_GRAPHS * 64, nN);
    aggr_kernel<HID><<<nbA, 256, 0, stream>>>(yB, t, row_ptr, csr_src, aRows, nN);
    transform_kernel<HID><<<nbT, 256, 0, stream>>>(aRows, yB, batch,
                                                   W3r, b3, W3s, yA, h + 2 * N_GRAPHS * 64, nN);
    mlp_kernel<<<N_GRAPHS, 128, 0, stream>>>(h, Wl1, bl1, Wl2, bl2, out);
}